// Round 8
// baseline (1004.248 us; speedup 1.0000x reference)
//
#include <hip/hip_runtime.h>
#include <hip/hip_bf16.h>

#define EPS 1e-5f
#define Bn 8
#define Cn 512
#define Nn 2304
#define C1n 256
#define C2n 256
#define CGn 128

typedef __bf16 bf16_t;
typedef __bf16 bf16x8 __attribute__((ext_vector_type(8)));
typedef float f32x4 __attribute__((ext_vector_type(4)));

#define MFMA16(a, b, c) __builtin_amdgcn_mfma_f32_16x16x32_bf16(a, b, c, 0, 0, 0)

// async global->LDS DMA, 16B per lane. LDS dest is wave-uniform base + lane*16.
__device__ __forceinline__ void gload16(const bf16_t* g, const bf16_t* l) {
  __builtin_amdgcn_global_load_lds(
      (const __attribute__((address_space(1))) void*)g,
      (__attribute__((address_space(3))) void*)l, 16, 0, 0);
}

// ---------- WPAR element offsets (bf16 weight arena) ----------
static constexpr size_t P_TW = 0;            // (4,256,512)
static constexpr size_t P_TB = 524288;
static constexpr size_t P_PW = 525312;
static constexpr size_t P_PB = 1049600;
static constexpr size_t P_GW = 1050624;
static constexpr size_t P_GB = 1574912;
static constexpr size_t P_WW = 1575936;      // (4,128,256)
static constexpr size_t P_WB = 1707008;
static constexpr size_t P_WG = 1707520;
static constexpr size_t P_WBE = 1708032;
static constexpr size_t P_BCW = 1708544;     // (512,1024)
static constexpr size_t P_BCB = 2232832;
static constexpr size_t P_BCG = 2233344;
static constexpr size_t P_BCBE = 2233856;

// ---------- workspace layout (bytes); end = 79,992,832 (proven safe) ----------
static constexpr size_t OFF_WPAR  = 0;          // 4,468,736
static constexpr size_t OFF_BIASF = 4468736;
static constexpr size_t OFF_SW    = 4470784;
static constexpr size_t OFF_TW2   = 4472832;
static constexpr size_t OFF_SO    = 4474880;
static constexpr size_t OFF_TO    = 4476928;
static constexpr size_t OFF_STATW = 4478976;    // f64[1024]
static constexpr size_t OFF_STATO = 4487168;    // f64[1024]
static constexpr size_t OFF_ARENA = 4495360;    // 32 slots x (K+V) = 75,497,472
static constexpr size_t QS  = 589824;           // elems: 2304*256
static constexpr size_t SL2 = 2 * QS;           // elems per slot (K,V)
// post-attn overlays inside the dead arena:
static constexpr size_t OVL_BCWF = OFF_ARENA;             // 1,048,576
static constexpr size_t OVL_UN   = OFF_ARENA + 2097152;   // 37,748,736 (unnormalized f32 out)
// d_out partitioning during the run:
//   [0, 18874368)        : wy scratch (bf16), written by attn, read by stats/final
//   [18874368, 37748736) : xbfT (bf16 [B][N][C]), written by k_xpose, read by
//                          projKV / k_final; clobbered only by k_norm at the end
static constexpr size_t OFF_XBFT_IN_OUT = 18874368;

// ---------- K0: convert 14 f32 weight inputs -> bf16 WPAR ----------
struct WArgs {
  const float* src[14];
  unsigned n[14];
  unsigned off[14];
};

__global__ __launch_bounds__(256) void k_wconv(WArgs a, bf16_t* __restrict__ par) {
  int which = blockIdx.y;
  const float* s = a.src[which];
  unsigned n = a.n[which];
  bf16_t* dst = par + a.off[which];
  size_t stride = (size_t)gridDim.x * blockDim.x;
  for (size_t i = (size_t)blockIdx.x * blockDim.x + threadIdx.x; i < n; i += stride)
    dst[i] = (bf16_t)s[i];
}

// ---------- K0b: feats (B,C,N) f32 -> xbfT (B,N,C) bf16 via LDS tile transpose ----------
__global__ __launch_bounds__(256) void k_xpose(const float* __restrict__ feats,
                                               bf16_t* __restrict__ xbfT) {
  __shared__ bf16_t tile[64][72];
  int b = blockIdx.z, c0 = blockIdx.y * 64, n0 = blockIdx.x * 64;
  int tid = threadIdx.x;
  int cl = tid >> 4, nl4 = (tid & 15) * 4;
#pragma unroll
  for (int e = 0; e < 4; e++) {
    int c = e * 16 + cl;
    float4 v = *(const float4*)(feats + ((size_t)b * Cn + c0 + c) * Nn + n0 + nl4);
    tile[nl4 + 0][c] = (bf16_t)v.x;
    tile[nl4 + 1][c] = (bf16_t)v.y;
    tile[nl4 + 2][c] = (bf16_t)v.z;
    tile[nl4 + 3][c] = (bf16_t)v.w;
  }
  __syncthreads();
  int r = tid >> 2, ch = tid & 3;
#pragma unroll
  for (int e = 0; e < 2; e++) {
    int cc = (ch + e * 4) * 8;  // 0..63
    bf16x8 v = *(const bf16x8*)(&tile[r][cc]);
    *(bf16x8*)(xbfT + ((size_t)b * Nn + n0 + r) * Cn + c0 + cc) = v;
  }
}

// ---------- K1: K (phi) and V (g) projections; X-tile staged in LDS (bf16x8), W direct ----------
// z = slot*2 + p (p=0: K (N,256) CHUNK-SWIZZLED; p=1: V (256,N))
__global__ __launch_bounds__(256) void k_projKV(
    const bf16_t* __restrict__ xbfT, const bf16_t* __restrict__ par,
    bf16_t* __restrict__ arena) {
  __shared__ alignas(16) bf16_t xsT[64][40];
  int z = blockIdx.z, s = z >> 1, p = z & 1;
  int g = s >> 3, b = s & 7;
  int tid = threadIdx.x, w = tid >> 6, lane = tid & 63;
  int l15 = lane & 15, quad = lane >> 4;
  int srow = tid >> 2, sch = (tid & 3) * 8;
  int n0 = blockIdx.x * 64;  // n-rows (m for p=0)
  const bf16_t* xsrc = xbfT + ((size_t)b * Nn + n0 + srow) * Cn + sch;

  if (p == 0) {
    const bf16_t* W = par + P_PW + (size_t)g * C1n * Cn;
    const bf16_t* bias = par + P_PB + g * C1n;
    bf16_t* out = arena + (size_t)s * SL2;
    int o0 = blockIdx.y * 64;
    f32x4 acc[4];
#pragma unroll
    for (int j = 0; j < 4; j++) acc[j] = (f32x4){0.f, 0.f, 0.f, 0.f};
    for (int kk = 0; kk < 16; kk++) {
      int c0 = kk * 32;
      __syncthreads();
      *(bf16x8*)(&xsT[srow][sch]) = *(const bf16x8*)(xsrc + c0);
      __syncthreads();
      bf16x8 a = *(const bf16x8*)(&xsT[w * 16 + l15][quad * 8]);
#pragma unroll
      for (int j = 0; j < 4; j++) {
        bf16x8 bw = *(const bf16x8*)(W + (size_t)(o0 + j * 16 + l15) * Cn + c0 + quad * 8);
        acc[j] = MFMA16(a, bw, acc[j]);
      }
    }
#pragma unroll
    for (int j = 0; j < 4; j++) {
      int col = o0 + j * 16 + l15;
      int chk = col >> 3, ci = col & 7;
      float bv = (float)bias[col];
#pragma unroll
      for (int r = 0; r < 4; r++) {
        int row = n0 + w * 16 + quad * 4 + r;
        out[(size_t)row * C1n + ((chk ^ (row & 7)) << 3) + ci] = (bf16_t)(acc[j][r] + bv);
      }
    }
  } else {
    const bf16_t* W = par + P_GW + (size_t)g * C2n * Cn;
    const bf16_t* bias = par + P_GB + g * C2n;
    bf16_t* out = arena + (size_t)s * SL2 + QS;
    int c20 = blockIdx.y * 64 + w * 16;
    f32x4 acc[4];
#pragma unroll
    for (int j = 0; j < 4; j++) acc[j] = (f32x4){0.f, 0.f, 0.f, 0.f};
    for (int kk = 0; kk < 16; kk++) {
      int c0 = kk * 32;
      __syncthreads();
      *(bf16x8*)(&xsT[srow][sch]) = *(const bf16x8*)(xsrc + c0);
      __syncthreads();
      bf16x8 a = *(const bf16x8*)(W + (size_t)(c20 + l15) * Cn + c0 + quad * 8);
#pragma unroll
      for (int j = 0; j < 4; j++) {
        bf16x8 bx = *(const bf16x8*)(&xsT[j * 16 + l15][quad * 8]);
        acc[j] = MFMA16(a, bx, acc[j]);
      }
    }
#pragma unroll
    for (int r = 0; r < 4; r++) {
      int row = c20 + quad * 4 + r;
      float bv = (float)bias[row];
#pragma unroll
      for (int j = 0; j < 4; j++)
        out[(size_t)row * Nn + n0 + j * 16 + l15] = (bf16_t)(acc[j][r] + bv);
    }
  }
}

// ---------- K2: attention, 128 rows/block, 8 waves x 16 rows, on-the-fly Q ----------
// R6 post-mortem: all pipes idle, Occupancy 14.7% ~ one 4-wave block/CU; limiter
// is unified VGPR+AGPR (~290/wave). This version: 512 threads, 8 waves x 16 rows
// -> per-wave state halves (qf 8, oacc 16, qacc 16) ~ <=170 regs -> full 8-wave
// block resident (25% occ), shorter dependency chains. Same math/swizzles as R6.
// LDS: K0|K1 [32x256]x2, V0|V1 [256x32]x2, pw 8x16x40 = 75,776 B.
__global__ __launch_bounds__(512, 2) void k_attn_wy(
    const float* __restrict__ feats, const bf16_t* __restrict__ arena,
    const bf16_t* __restrict__ par, bf16_t* __restrict__ wyOut) {
  __shared__ alignas(16) bf16_t sh[32768 + 5120];

  int mblk = blockIdx.x, gb = blockIdx.y;
  int g = gb >> 3, b = gb & 7;
  const bf16_t* Kp = arena + (size_t)gb * SL2;
  const bf16_t* Vp = Kp + QS;

  int tid = threadIdx.x, w = tid >> 6, lane = tid & 63;
  int l15 = lane & 15, quad = lane >> 4;
  int m0 = mblk * 128;
  int mw0 = m0 + w * 16;          // 16 rows per wave
  int w64 = w << 6;
  bf16_t* pw = sh + 32768 + w * 640;  // per-wave 16x40

  // ---- phase Q: qf[kc8] = Q A-frags for this wave's 16 rows ----
  bf16x8 qf[8];
  {
    bf16_t* xs = sh + 24576 + w * 640;  // per-wave 16x40 scratch (V1 region)
    const bf16_t* Wt = par + P_TW + (size_t)g * C1n * Cn;
    const bf16_t* tb = par + P_TB + g * C1n;
    f32x4 qacc[16];
#pragma unroll
    for (int ot = 0; ot < 16; ot++) qacc[ot] = (f32x4){0.f, 0.f, 0.f, 0.f};

    for (int kc = 0; kc < 16; kc++) {
      // stage own 16 rows x 32 c (wave-private, no barrier) — float4 vectorized
#pragma unroll
      for (int ps = 0; ps < 2; ps++) {
        int idx = ps * 64 + lane;        // 0..127
        int cc = idx & 31;               // col 0..31
        int nn = (idx >> 5) * 4;         // row group 0,4,8,12
        const float4 v =
            *(const float4*)(feats + ((size_t)b * Cn + kc * 32 + cc) * Nn + mw0 + nn);
        xs[(nn + 0) * 40 + cc] = (bf16_t)v.x;
        xs[(nn + 1) * 40 + cc] = (bf16_t)v.y;
        xs[(nn + 2) * 40 + cc] = (bf16_t)v.z;
        xs[(nn + 3) * 40 + cc] = (bf16_t)v.w;
      }
      bf16x8 a = *(const bf16x8*)(xs + l15 * 40 + quad * 8);
#pragma unroll
      for (int ot = 0; ot < 16; ot++) {
        bf16x8 bw = *(const bf16x8*)(Wt + (size_t)(ot * 16 + l15) * Cn + kc * 32 + quad * 8);
        qacc[ot] = MFMA16(a, bw, qacc[ot]);
      }
    }
    // C-layout -> A-frags via per-wave roundtrip (pw, 16x40)
#pragma unroll
    for (int kc8 = 0; kc8 < 8; kc8++) {
#pragma unroll
      for (int h = 0; h < 2; h++) {
        int ot = kc8 * 2 + h;
        float bv = (float)tb[ot * 16 + l15];
#pragma unroll
        for (int r = 0; r < 4; r++)
          pw[(quad * 4 + r) * 40 + h * 16 + l15] = (bf16_t)(qacc[ot][r] + bv);
      }
      qf[kc8] = *(const bf16x8*)(pw + l15 * 40 + quad * 8);
    }
  }

  // ---- accumulators ----
  f32x4 oacc[16];
#pragma unroll
  for (int ct = 0; ct < 16; ct++) oacc[ct] = (f32x4){0.f, 0.f, 0.f, 0.f};
  f32x4 lacc = (f32x4){0.f, 0.f, 0.f, 0.f};

  bf16x8 ones;
#pragma unroll
  for (int i = 0; i < 8; i++) ones[i] = (bf16_t)1.0f;
  const float SC = 0.0625f * 1.44269504088896f;  // exp(f/16) = exp2(f*SC)

  // ---- prologue: stage tile 0 into buffer 0 (after phase Q) ----
#pragma unroll
  for (int e = 0; e < 2; e++) {
    int cid = e * 512 + tid;
    gload16(Kp + (size_t)(cid >> 5) * C1n + ((cid & 31) << 3),
            sh + ((e << 9) + w64) * 8);
    // V source chunk swizzled: chunk' = (cid&3) ^ ((row>>1)&3), row = cid>>2
    gload16(Vp + (size_t)(cid >> 2) * Nn + ((((cid & 3) ^ ((cid >> 3) & 3))) << 3),
            sh + 16384 + ((e << 9) + w64) * 8);
  }
  __syncthreads();  // implicit vmcnt(0): tile 0 resident

  int cur = 0;
  int xrk = l15 & 7;          // K read swizzle key (row&7)
  int xrv = (l15 >> 1) & 3;   // V read swizzle key ((row>>1)&3)
  for (int t = 0; t < 72; t++) {
    // issue async stage of tile t+1 into the other buffer (overlaps compute)
    if (t < 71) {
      int nn0 = (t + 1) * 32;
      bf16_t* kd = sh + (cur ^ 1) * 8192;
      bf16_t* vd = sh + 16384 + (cur ^ 1) * 8192;
#pragma unroll
      for (int e = 0; e < 2; e++) {
        int cid = e * 512 + tid;
        gload16(Kp + (size_t)(nn0 + (cid >> 5)) * C1n + ((cid & 31) << 3),
                kd + ((e << 9) + w64) * 8);
        gload16(Vp + (size_t)(cid >> 2) * Nn + nn0 + ((((cid & 3) ^ ((cid >> 3) & 3))) << 3),
                vd + ((e << 9) + w64) * 8);
      }
    }
    const bf16_t* kbuf = sh + cur * 8192;          // [32][256], chunk-swizzled
    const bf16_t* vbuf = sh + 16384 + cur * 8192;  // [256][32], chunk-swizzled

    // QK: 2 nt key-subtiles
    f32x4 sacc[2];
    sacc[0] = (f32x4){0.f, 0.f, 0.f, 0.f};
    sacc[1] = (f32x4){0.f, 0.f, 0.f, 0.f};
    __builtin_amdgcn_s_setprio(1);
#pragma unroll
    for (int ks = 0; ks < 8; ks++) {
#pragma unroll
      for (int nt = 0; nt < 2; nt++) {
        bf16x8 kb = *(const bf16x8*)(kbuf + (nt * 16 + l15) * 256 +
                                     (((ks * 4 + quad) ^ xrk) << 3));
        sacc[nt] = MFMA16(qf[ks], kb, sacc[nt]);
      }
    }
    __builtin_amdgcn_s_setprio(0);
    // exp -> P (bf16, per-wave roundtrip)
#pragma unroll
    for (int nt = 0; nt < 2; nt++)
#pragma unroll
      for (int r = 0; r < 4; r++)
        pw[(quad * 4 + r) * 40 + nt * 16 + l15] = (bf16_t)exp2f(sacc[nt][r] * SC);
    bf16x8 pa = *(const bf16x8*)(pw + l15 * 40 + quad * 8);
    lacc = MFMA16(pa, ones, lacc);
    // PV
    __builtin_amdgcn_s_setprio(1);
#pragma unroll
    for (int ct = 0; ct < 16; ct++) {
      bf16x8 vb = *(const bf16x8*)(vbuf + (ct * 16 + l15) * 32 +
                                   ((quad ^ xrv) << 3));
      oacc[ct] = MFMA16(pa, vb, oacc[ct]);
    }
    __builtin_amdgcn_s_setprio(0);
    __syncthreads();  // tile t+1 resident; all waves done with buf[cur]
    cur ^= 1;
  }

  float inv[4];
#pragma unroll
  for (int r = 0; r < 4; r++) inv[r] = 1.f / lacc[r];

  // ---- epilogue: y -> A-frags -> W-conv -> wy (d_out scratch) ----
  const bf16_t* Wg = par + P_WW + (size_t)g * CGn * C2n;
  const bf16_t* wbias = par + P_WB + g * CGn;
  bf16x8 yf[8];
#pragma unroll
  for (int kc8 = 0; kc8 < 8; kc8++) {
#pragma unroll
    for (int h = 0; h < 2; h++) {
      int ct = kc8 * 2 + h;
#pragma unroll
      for (int r = 0; r < 4; r++)
        pw[(quad * 4 + r) * 40 + h * 16 + l15] = (bf16_t)(oacc[ct][r] * inv[r]);
    }
    yf[kc8] = *(const bf16x8*)(pw + l15 * 40 + quad * 8);
  }
#pragma unroll
  for (int ot = 0; ot < 8; ot++) {
    f32x4 wyacc = (f32x4){0.f, 0.f, 0.f, 0.f};
#pragma unroll
    for (int ks = 0; ks < 8; ks++) {
      bf16x8 wv = *(const bf16x8*)(Wg + (size_t)(ot * 16 + l15) * C2n + ks * 32 + quad * 8);
      wyacc = MFMA16(yf[ks], wv, wyacc);
    }
    int o = ot * 16 + l15;
    float bv = (float)wbias[o];
#pragma unroll
    for (int r = 0; r < 4; r++)
      wyOut[((size_t)b * Nn + mw0 + quad * 4 + r) * 512 + g * 128 + o] =
          (bf16_t)(wyacc[r] + bv);
  }
}

// ---------- wy BN stats: vectorized bf16x8 reads + LDS f32 reduce ----------
__global__ __launch_bounds__(256) void k_wy_stats(const bf16_t* __restrict__ wyBF,
                                                  double* __restrict__ stats) {
  __shared__ float sred[1024];
  int b = blockIdx.y, m0 = blockIdx.x * 64, tid = threadIdx.x;
  for (int i = tid; i < 1024; i += 256) sred[i] = 0.f;
  __syncthreads();
  int ch8 = (tid & 63) * 8, r0 = tid >> 6;
  float s[8], q[8];
#pragma unroll
  for (int j = 0; j < 8; j++) { s[j] = 0.f; q[j] = 0.f; }
  for (int k = 0; k < 16; k++) {
    int row = k * 4 + r0;
    bf16x8 v = *(const bf16x8*)(wyBF + ((size_t)b * Nn + m0 + row) * 512 + ch8);
#pragma unroll
    for (int j = 0; j < 8; j++) {
      float f = (float)v[j];
      s[j] += f;
      q[j] += f * f;
    }
  }
#pragma unroll
  for (int j = 0; j < 8; j++) {
    atomicAdd(&sred[ch8 + j], s[j]);
    atomicAdd(&sred[512 + ch8 + j], q[j]);
  }
  __syncthreads();
  for (int i = tid; i < 1024; i += 256) atomicAdd(&stats[i], (double)sred[i]);
}

// ---------- BN scale/shift ----------
__global__ void k_bn_st(const double* __restrict__ stats, const bf16_t* __restrict__ gamma,
                        const bf16_t* __restrict__ beta, float* __restrict__ sArr,
                        float* __restrict__ tArr, double inv_count) {
  int ch = threadIdx.x;  // 512
  double mean = stats[ch] * inv_count;
  double var = stats[512 + ch] * inv_count - mean * mean;
  double s = (double)(float)gamma[ch] / sqrt(var + (double)EPS);
  sArr[ch] = (float)s;
  tArr[ch] = (float)((double)(float)beta[ch] - mean * s);
}

// ---------- fold wy-BN into bottleneck weights ----------
__global__ __launch_bounds__(256) void k_fold(
    const bf16_t* __restrict__ par, const float* __restrict__ sW,
    const float* __restrict__ tW, bf16_t* __restrict__ bcwF, float* __restrict__ biasF) {
  int oo = blockIdx.x;
  int tid = threadIdx.x;
  const bf16_t* row = par + P_BCW + (size_t)oo * 1024;
  bf16_t* orow = bcwF + (size_t)oo * 1024;
  float part = 0.f;
  for (int c = tid; c < 512; c += 256) orow[c] = row[c];
  for (int c = 512 + tid; c < 1024; c += 256) {
    float wv = (float)row[c];
    orow[c] = (bf16_t)(wv * sW[c - 512]);
    part += wv * tW[c - 512];
  }
  __shared__ float red[256];
  red[tid] = part;
  __syncthreads();
  for (int s = 128; s > 0; s >>= 1) {
    if (tid < s) red[tid] += red[tid + s];
    __syncthreads();
  }
  if (tid == 0) biasF[oo] = (float)par[P_BCB + oo] + red[0];
}

// ---------- final GEMM (single pass): stats + unnormalized f32 out ----------
// X-tile staged through LDS (bf16x8); wy B-frags direct-global (R1 structure).
__global__ __launch_bounds__(256) void k_final(
    const bf16_t* __restrict__ xbfT, const bf16_t* __restrict__ wyBF,
    const bf16_t* __restrict__ bcwF, const float* __restrict__ biasF,
    double* __restrict__ stats, float* __restrict__ un) {
  __shared__ alignas(16) bf16_t xsT[64][40];
  int b = blockIdx.z;
  int tid = threadIdx.x, w = tid >> 6, lane = tid & 63;
  int l15 = lane & 15, quad = lane >> 4;
  int oo0 = blockIdx.y * 64 + w * 16;
  int n0 = blockIdx.x * 64;
  int srow = tid >> 2, sch = (tid & 3) * 8;
  const bf16_t* xsrc = xbfT + ((size_t)b * Nn + n0 + srow) * Cn + sch;

  f32x4 acc[4];
#pragma unroll
  for (int j = 0; j < 4; j++) acc[j] = (f32x4){0.f, 0.f, 0.f, 0.f};

  for (int kk = 0; kk < 16; kk++) {
    int c0 = kk * 32;
    __syncthreads();
    *(bf16x8*)(&xsT[srow][sch]) = *(const bf16x8*)(xsrc + c0);
    __syncthreads();
    bf16x8 a = *(const bf16x8*)(bcwF + (size_t)(oo0 + l15) * 1024 + c0 + quad * 8);
#pragma unroll
    for (int j = 0; j < 4; j++) {
      bf16x8 bx = *(const bf16x8*)(&xsT[j * 16 + l15][quad * 8]);
      acc[j] = MFMA16(a, bx, acc[j]);
    }
  }
  for (int kk = 0; kk < 16; kk++) {
    int c0 = kk * 32 + quad * 8;
    bf16x8 a = *(const bf16x8*)(bcwF + (size_t)(oo0 + l15) * 1024 + 512 + c0);
#pragma unroll
    for (int j = 0; j < 4; j++) {
      bf16x8 bw = *(const bf16x8*)(wyBF + ((size_t)b * Nn + n0 + j * 16 + l15) * 512 + c0);
      acc[j] = MFMA16(a, bw, acc[j]);
    }
  }

#pragma unroll
  for (int r = 0; r < 4; r++) {
    int row = oo0 + quad * 4 + r;
    float bv = biasF[row];
    float s = 0.f, q = 0.f;
#pragma unroll
    for (int j = 0; j < 4; j++) {
      float v = acc[j][r] + bv;
      un[((size_t)b * 512 + row) * Nn + n0 + j * 16 + l15] = v;
      s += v;
      q += v * v;
    }
    s += __shfl_xor(s, 1); q += __shfl_xor(q, 1);
    s += __shfl_xor(s, 2); q += __shfl_xor(q, 2);
    s += __shfl_xor(s, 4); q += __shfl_xor(q, 4);
    s += __shfl_xor(s, 8); q += __shfl_xor(q, 8);
    if (l15 == 0) {
      atomicAdd(&stats[row], (double)s);
      atomicAdd(&stats[512 + row], (double)q);
    }
  }
}

// ---------- elementwise normalize: out = un*s[ch] + t[ch] ----------
__global__ __launch_bounds__(256) void k_norm(const float4* __restrict__ un,
                                              const float* __restrict__ sO,
                                              const float* __restrict__ tO,
                                              float4* __restrict__ out) {
  size_t i = (size_t)blockIdx.x * 256 + threadIdx.x;
  if (i >= (size_t)2359296) return;        // 8*512*2304/4
  size_t r = i / 576;                      // b*512 + ch (576 float4 per row)
  int ch = (int)(r & 511);
  float sc = sO[ch], tc = tO[ch];
  float4 v = un[i];
  float4 o;
  o.x = v.x * sc + tc;
  o.y = v.y * sc + tc;
  o.z = v.z * sc + tc;
  o.w = v.w * sc + tc;
  out[i] = o;
}

extern "C" void kernel_launch(void* const* d_in, const int* in_sizes, int n_in,
                              void* d_out, int out_size, void* d_ws, size_t ws_size,
                              hipStream_t stream) {
  const float* feats = (const float*)d_in[0];

  char* ws = (char*)d_ws;
  bf16_t* WPAR = (bf16_t*)(ws + OFF_WPAR);
  float* biasF = (float*)(ws + OFF_BIASF);
  float* sW = (float*)(ws + OFF_SW);
  float* tW = (float*)(ws + OFF_TW2);
  float* sO = (float*)(ws + OFF_SO);
  float* tO = (float*)(ws + OFF_TO);
  double* statsWy = (double*)(ws + OFF_STATW);
  double* statsO = (double*)(ws + OFF_STATO);
  bf16_t* arena = (bf16_t*)(ws + OFF_ARENA);
  bf16_t* bcwF = (bf16_t*)(ws + OVL_BCWF);     // post-attn overlay
  float* unScr = (float*)(ws + OVL_UN);        // post-attn overlay (unnormalized out)
  bf16_t* wyScr = (bf16_t*)d_out;              // d_out lower half: wy scratch
  bf16_t* xbfT = (bf16_t*)((char*)d_out + OFF_XBFT_IN_OUT);  // d_out upper half

  static const unsigned par_off[14] = {
      (unsigned)P_TW, (unsigned)P_TB, (unsigned)P_PW, (unsigned)P_PB,
      (unsigned)P_GW, (unsigned)P_GB, (unsigned)P_WW, (unsigned)P_WB,
      (unsigned)P_WG, (unsigned)P_WBE, (unsigned)P_BCW, (unsigned)P_BCB,
      (unsigned)P_BCG, (unsigned)P_BCBE};
  WArgs wa;
  for (int i = 0; i < 14; i++) {
    wa.src[i] = (const float*)d_in[i + 1];
    wa.n[i] = (unsigned)in_sizes[i + 1];
    wa.off[i] = par_off[i];
  }

  hipMemsetAsync(ws + OFF_STATW, 0, 16384, stream);  // statsWy + statsO

  k_wconv<<<dim3(256, 14), 256, 0, stream>>>(wa, WPAR);
  k_xpose<<<dim3(36, 8, 8), 256, 0, stream>>>(feats, xbfT);
  k_projKV<<<dim3(36, 4, 64), 256, 0, stream>>>(xbfT, WPAR, arena);
  k_attn_wy<<<dim3(18, 32), 512, 0, stream>>>(feats, arena, WPAR, wyScr);
  k_wy_stats<<<dim3(36, 8), 256, 0, stream>>>(wyScr, statsWy);
  k_bn_st<<<1, 512, 0, stream>>>(statsWy, WPAR + P_WG, WPAR + P_WBE, sW, tW, 1.0 / 18432.0);
  k_fold<<<512, 256, 0, stream>>>(WPAR, sW, tW, bcwF, biasF);
  k_final<<<dim3(36, 8, 8), 256, 0, stream>>>(xbfT, wyScr, bcwF, biasF, statsO, unScr);
  k_bn_st<<<1, 512, 0, stream>>>(statsO, WPAR + P_BCG, WPAR + P_BCBE, sO, tO, 1.0 / 18432.0);
  k_norm<<<9216, 256, 0, stream>>>((const float4*)unScr, sO, tO, (float4*)d_out);
}

// Round 9
// 941.133 us; speedup vs baseline: 1.0671x; 1.0671x over previous
//
#include <hip/hip_runtime.h>
#include <hip/hip_bf16.h>

#define EPS 1e-5f
#define Bn 8
#define Cn 512
#define Nn 2304
#define C1n 256
#define C2n 256
#define CGn 128

typedef __bf16 bf16_t;
typedef __bf16 bf16x8 __attribute__((ext_vector_type(8)));
typedef float f32x4 __attribute__((ext_vector_type(4)));

#define MFMA16(a, b, c) __builtin_amdgcn_mfma_f32_16x16x32_bf16(a, b, c, 0, 0, 0)

// async global->LDS DMA, 16B per lane. LDS dest is wave-uniform base + lane*16.
__device__ __forceinline__ void gload16(const bf16_t* g, const bf16_t* l) {
  __builtin_amdgcn_global_load_lds(
      (const __attribute__((address_space(1))) void*)g,
      (__attribute__((address_space(3))) void*)l, 16, 0, 0);
}

// ---------- WPAR element offsets (bf16 weight arena) ----------
static constexpr size_t P_TW = 0;            // (4,256,512)
static constexpr size_t P_TB = 524288;
static constexpr size_t P_PW = 525312;
static constexpr size_t P_PB = 1049600;
static constexpr size_t P_GW = 1050624;
static constexpr size_t P_GB = 1574912;
static constexpr size_t P_WW = 1575936;      // (4,128,256)
static constexpr size_t P_WB = 1707008;
static constexpr size_t P_WG = 1707520;
static constexpr size_t P_WBE = 1708032;
static constexpr size_t P_BCW = 1708544;     // (512,1024)
static constexpr size_t P_BCB = 2232832;
static constexpr size_t P_BCG = 2233344;
static constexpr size_t P_BCBE = 2233856;

// ---------- workspace layout (bytes); end = 79,992,832 (proven safe) ----------
static constexpr size_t OFF_WPAR  = 0;          // 4,468,736
static constexpr size_t OFF_BIASF = 4468736;
static constexpr size_t OFF_SW    = 4470784;
static constexpr size_t OFF_TW2   = 4472832;
static constexpr size_t OFF_SO    = 4474880;
static constexpr size_t OFF_TO    = 4476928;
static constexpr size_t OFF_STATW = 4478976;    // f64[1024]
static constexpr size_t OFF_STATO = 4487168;    // f64[1024]
static constexpr size_t OFF_ARENA = 4495360;    // 32 slots x (K+V) = 75,497,472
static constexpr size_t QS  = 589824;           // elems: 2304*256
static constexpr size_t SL2 = 2 * QS;           // elems per slot (K,V)
// post-attn overlays inside the dead arena:
static constexpr size_t OVL_BCWF = OFF_ARENA;             // 1,048,576
static constexpr size_t OVL_UN   = OFF_ARENA + 2097152;   // 37,748,736 (unnormalized f32 out)
// d_out partitioning during the run:
//   [0, 18874368)        : wy scratch (bf16), written by attn, read by stats/final
//   [18874368, 37748736) : xbfT (bf16 [B][N][C]), written by k_xpose, read by
//                          projKV / k_final; clobbered only by k_norm at the end
static constexpr size_t OFF_XBFT_IN_OUT = 18874368;

// ---------- K0: convert 14 f32 weight inputs -> bf16 WPAR ----------
struct WArgs {
  const float* src[14];
  unsigned n[14];
  unsigned off[14];
};

__global__ __launch_bounds__(256) void k_wconv(WArgs a, bf16_t* __restrict__ par) {
  int which = blockIdx.y;
  const float* s = a.src[which];
  unsigned n = a.n[which];
  bf16_t* dst = par + a.off[which];
  size_t stride = (size_t)gridDim.x * blockDim.x;
  for (size_t i = (size_t)blockIdx.x * blockDim.x + threadIdx.x; i < n; i += stride)
    dst[i] = (bf16_t)s[i];
}

// ---------- K0b: feats (B,C,N) f32 -> xbfT (B,N,C) bf16 via LDS tile transpose ----------
__global__ __launch_bounds__(256) void k_xpose(const float* __restrict__ feats,
                                               bf16_t* __restrict__ xbfT) {
  __shared__ bf16_t tile[64][72];
  int b = blockIdx.z, c0 = blockIdx.y * 64, n0 = blockIdx.x * 64;
  int tid = threadIdx.x;
  int cl = tid >> 4, nl4 = (tid & 15) * 4;
#pragma unroll
  for (int e = 0; e < 4; e++) {
    int c = e * 16 + cl;
    float4 v = *(const float4*)(feats + ((size_t)b * Cn + c0 + c) * Nn + n0 + nl4);
    tile[nl4 + 0][c] = (bf16_t)v.x;
    tile[nl4 + 1][c] = (bf16_t)v.y;
    tile[nl4 + 2][c] = (bf16_t)v.z;
    tile[nl4 + 3][c] = (bf16_t)v.w;
  }
  __syncthreads();
  int r = tid >> 2, ch = tid & 3;
#pragma unroll
  for (int e = 0; e < 2; e++) {
    int cc = (ch + e * 4) * 8;  // 0..63
    bf16x8 v = *(const bf16x8*)(&tile[r][cc]);
    *(bf16x8*)(xbfT + ((size_t)b * Nn + n0 + r) * Cn + c0 + cc) = v;
  }
}

// ---------- K1: K (phi) and V (g) projections; X-tile staged in LDS (bf16x8), W direct ----------
// z = slot*2 + p (p=0: K (N,256) CHUNK-SWIZZLED; p=1: V (256,N))
__global__ __launch_bounds__(256) void k_projKV(
    const bf16_t* __restrict__ xbfT, const bf16_t* __restrict__ par,
    bf16_t* __restrict__ arena) {
  __shared__ alignas(16) bf16_t xsT[64][40];
  int z = blockIdx.z, s = z >> 1, p = z & 1;
  int g = s >> 3, b = s & 7;
  int tid = threadIdx.x, w = tid >> 6, lane = tid & 63;
  int l15 = lane & 15, quad = lane >> 4;
  int srow = tid >> 2, sch = (tid & 3) * 8;
  int n0 = blockIdx.x * 64;  // n-rows (m for p=0)
  const bf16_t* xsrc = xbfT + ((size_t)b * Nn + n0 + srow) * Cn + sch;

  if (p == 0) {
    const bf16_t* W = par + P_PW + (size_t)g * C1n * Cn;
    const bf16_t* bias = par + P_PB + g * C1n;
    bf16_t* out = arena + (size_t)s * SL2;
    int o0 = blockIdx.y * 64;
    f32x4 acc[4];
#pragma unroll
    for (int j = 0; j < 4; j++) acc[j] = (f32x4){0.f, 0.f, 0.f, 0.f};
    for (int kk = 0; kk < 16; kk++) {
      int c0 = kk * 32;
      __syncthreads();
      *(bf16x8*)(&xsT[srow][sch]) = *(const bf16x8*)(xsrc + c0);
      __syncthreads();
      bf16x8 a = *(const bf16x8*)(&xsT[w * 16 + l15][quad * 8]);
#pragma unroll
      for (int j = 0; j < 4; j++) {
        bf16x8 bw = *(const bf16x8*)(W + (size_t)(o0 + j * 16 + l15) * Cn + c0 + quad * 8);
        acc[j] = MFMA16(a, bw, acc[j]);
      }
    }
#pragma unroll
    for (int j = 0; j < 4; j++) {
      int col = o0 + j * 16 + l15;
      int chk = col >> 3, ci = col & 7;
      float bv = (float)bias[col];
#pragma unroll
      for (int r = 0; r < 4; r++) {
        int row = n0 + w * 16 + quad * 4 + r;
        out[(size_t)row * C1n + ((chk ^ (row & 7)) << 3) + ci] = (bf16_t)(acc[j][r] + bv);
      }
    }
  } else {
    const bf16_t* W = par + P_GW + (size_t)g * C2n * Cn;
    const bf16_t* bias = par + P_GB + g * C2n;
    bf16_t* out = arena + (size_t)s * SL2 + QS;
    int c20 = blockIdx.y * 64 + w * 16;
    f32x4 acc[4];
#pragma unroll
    for (int j = 0; j < 4; j++) acc[j] = (f32x4){0.f, 0.f, 0.f, 0.f};
    for (int kk = 0; kk < 16; kk++) {
      int c0 = kk * 32;
      __syncthreads();
      *(bf16x8*)(&xsT[srow][sch]) = *(const bf16x8*)(xsrc + c0);
      __syncthreads();
      bf16x8 a = *(const bf16x8*)(W + (size_t)(c20 + l15) * Cn + c0 + quad * 8);
#pragma unroll
      for (int j = 0; j < 4; j++) {
        bf16x8 bx = *(const bf16x8*)(&xsT[j * 16 + l15][quad * 8]);
        acc[j] = MFMA16(a, bx, acc[j]);
      }
    }
#pragma unroll
    for (int r = 0; r < 4; r++) {
      int row = c20 + quad * 4 + r;
      float bv = (float)bias[row];
#pragma unroll
      for (int j = 0; j < 4; j++)
        out[(size_t)row * Nn + n0 + j * 16 + l15] = (bf16_t)(acc[j][r] + bv);
    }
  }
}

// ---------- K2: attention, 128 rows/block, 4 waves x 32 rows (R6 structure) ----------
// T4 counted-vmcnt pipeline: TRIPLE-buffered K/V, prefetch depth 2, raw s_barrier +
// s_waitcnt vmcnt(8) (newest 8 loads stay in flight across the barrier; never
// drain to 0 in the main loop). R0->R1 proved the per-iteration vmcnt(0) drain
// costs ~250us; this removes the remaining one.
// LDS: K0|K1|K2 [32x256] @0 | V0|V1|V2 [256x32] @24576 | pw 4x32x40 @49152
// = 54272 elems = 108.5 KB -> 1 block/CU (cross-block overlap proven weak).
__global__ __launch_bounds__(256) void k_attn_wy(
    const float* __restrict__ feats, const bf16_t* __restrict__ arena,
    const bf16_t* __restrict__ par, bf16_t* __restrict__ wyOut) {
  __shared__ alignas(16) bf16_t sh[54272];

  int mblk = blockIdx.x, gb = blockIdx.y;
  int g = gb >> 3, b = gb & 7;
  const bf16_t* Kp = arena + (size_t)gb * SL2;
  const bf16_t* Vp = Kp + QS;

  int tid = threadIdx.x, w = tid >> 6, lane = tid & 63;
  int l15 = lane & 15, quad = lane >> 4;
  int m0 = mblk * 128;
  int mw0 = m0 + w * 32;
  int w64 = w << 6;
  bf16_t* pw = sh + 49152 + w * 1280;  // per-wave 32x40

  // ---- phase Q: qf[rt*8+kc8] = Q A-frags for this wave's 32 rows ----
  // xs == pw (per-wave private, disjoint in time within the wave).
  bf16x8 qf[16];
  {
    bf16_t* xs = pw;
    const bf16_t* Wt = par + P_TW + (size_t)g * C1n * Cn;
    const bf16_t* tb = par + P_TB + g * C1n;
    f32x4 qacc[2][16];
#pragma unroll
    for (int rt = 0; rt < 2; rt++)
#pragma unroll
      for (int ot = 0; ot < 16; ot++) qacc[rt][ot] = (f32x4){0.f, 0.f, 0.f, 0.f};

    for (int kc = 0; kc < 16; kc++) {
      // stage own 32 rows x 32 c (wave-private, no barrier) — float4 vectorized
#pragma unroll
      for (int ps = 0; ps < 4; ps++) {
        int idx = ps * 64 + lane;
        int cc = idx >> 3;           // ps*8 + lane>>3, 0..31
        int nn = (idx & 7) * 4;
        const float4 v =
            *(const float4*)(feats + ((size_t)b * Cn + kc * 32 + cc) * Nn + mw0 + nn);
        xs[(nn + 0) * 40 + cc] = (bf16_t)v.x;
        xs[(nn + 1) * 40 + cc] = (bf16_t)v.y;
        xs[(nn + 2) * 40 + cc] = (bf16_t)v.z;
        xs[(nn + 3) * 40 + cc] = (bf16_t)v.w;
      }
#pragma unroll
      for (int rt = 0; rt < 2; rt++) {
        bf16x8 a = *(const bf16x8*)(xs + (rt * 16 + l15) * 40 + quad * 8);
#pragma unroll
        for (int ot = 0; ot < 16; ot++) {
          bf16x8 bw = *(const bf16x8*)(Wt + (size_t)(ot * 16 + l15) * Cn + kc * 32 + quad * 8);
          qacc[rt][ot] = MFMA16(a, bw, qacc[rt][ot]);
        }
      }
    }
    // C-layout -> A-frags via per-wave roundtrip (pw, 32x40)
#pragma unroll
    for (int rt = 0; rt < 2; rt++)
#pragma unroll
      for (int kc8 = 0; kc8 < 8; kc8++) {
#pragma unroll
        for (int h = 0; h < 2; h++) {
          int ot = kc8 * 2 + h;
          float bv = (float)tb[ot * 16 + l15];
#pragma unroll
          for (int r = 0; r < 4; r++)
            pw[(quad * 4 + r) * 40 + h * 16 + l15] = (bf16_t)(qacc[rt][ot][r] + bv);
        }
        qf[rt * 8 + kc8] = *(const bf16x8*)(pw + l15 * 40 + quad * 8);
      }
  }

  // ---- accumulators ----
  f32x4 oacc[2][16];
#pragma unroll
  for (int rt = 0; rt < 2; rt++)
#pragma unroll
    for (int ct = 0; ct < 16; ct++) oacc[rt][ct] = (f32x4){0.f, 0.f, 0.f, 0.f};
  f32x4 lacc[2];
  lacc[0] = (f32x4){0.f, 0.f, 0.f, 0.f};
  lacc[1] = (f32x4){0.f, 0.f, 0.f, 0.f};

  bf16x8 ones;
#pragma unroll
  for (int i = 0; i < 8; i++) ones[i] = (bf16_t)1.0f;
  const float SC = 0.0625f * 1.44269504088896f;  // exp(f/16) = exp2(f*SC)

  // ---- prologue: issue tiles 0 and 1 (16 loads/thread) ----
#pragma unroll
  for (int e = 0; e < 4; e++) {
    int cid = e * 256 + tid;
    gload16(Kp + (size_t)(cid >> 5) * C1n + ((cid & 31) << 3),
            sh + ((e << 8) + w64) * 8);
    gload16(Vp + (size_t)(cid >> 2) * Nn + ((((cid & 3) ^ ((cid >> 3) & 3))) << 3),
            sh + 24576 + ((e << 8) + w64) * 8);
  }
#pragma unroll
  for (int e = 0; e < 4; e++) {
    int cid = e * 256 + tid;
    gload16(Kp + (size_t)(32 + (cid >> 5)) * C1n + ((cid & 31) << 3),
            sh + 8192 + ((e << 8) + w64) * 8);
    gload16(Vp + (size_t)(cid >> 2) * Nn + 32 + ((((cid & 3) ^ ((cid >> 3) & 3))) << 3),
            sh + 24576 + 8192 + ((e << 8) + w64) * 8);
  }
  // tile 0 resident (oldest 8 retired); tile 1 may stay in flight
  asm volatile("s_waitcnt vmcnt(8)" ::: "memory");
  __builtin_amdgcn_s_barrier();
  __builtin_amdgcn_sched_barrier(0);

  int bc = 0;                 // buffer index of current tile (mod 3)
  int xrk = l15 & 7;          // K read swizzle key (row&7)
  int xrv = (l15 >> 1) & 3;   // V read swizzle key ((row>>1)&3)
  for (int t = 0; t < 72; t++) {
    // issue async stage of tile t+2 (depth-2 prefetch)
    if (t < 70) {
      int nn0 = (t + 2) * 32;
      int b2 = bc + 2; if (b2 >= 3) b2 -= 3;
      bf16_t* kd = sh + b2 * 8192;
      bf16_t* vd = sh + 24576 + b2 * 8192;
#pragma unroll
      for (int e = 0; e < 4; e++) {
        int cid = e * 256 + tid;
        gload16(Kp + (size_t)(nn0 + (cid >> 5)) * C1n + ((cid & 31) << 3),
                kd + ((e << 8) + w64) * 8);
        gload16(Vp + (size_t)(cid >> 2) * Nn + nn0 + ((((cid & 3) ^ ((cid >> 3) & 3))) << 3),
                vd + ((e << 8) + w64) * 8);
      }
    }
    const bf16_t* kbuf = sh + bc * 8192;          // [32][256], chunk-swizzled
    const bf16_t* vbuf = sh + 24576 + bc * 8192;  // [256][32], chunk-swizzled

    // QK: 2 rt x 2 nt, each B-read feeds 2 MFMA (swizzled chunk read)
    f32x4 sacc[2][2];
#pragma unroll
    for (int rt = 0; rt < 2; rt++)
#pragma unroll
      for (int nt = 0; nt < 2; nt++) sacc[rt][nt] = (f32x4){0.f, 0.f, 0.f, 0.f};
    __builtin_amdgcn_s_setprio(1);
#pragma unroll
    for (int ks = 0; ks < 8; ks++) {
#pragma unroll
      for (int nt = 0; nt < 2; nt++) {
        bf16x8 kb = *(const bf16x8*)(kbuf + (nt * 16 + l15) * 256 +
                                     (((ks * 4 + quad) ^ xrk) << 3));
        sacc[0][nt] = MFMA16(qf[ks], kb, sacc[0][nt]);
        sacc[1][nt] = MFMA16(qf[8 + ks], kb, sacc[1][nt]);
      }
    }
    __builtin_amdgcn_s_setprio(0);
    // exp -> P (bf16, per-wave roundtrip)
#pragma unroll
    for (int rt = 0; rt < 2; rt++)
#pragma unroll
      for (int nt = 0; nt < 2; nt++)
#pragma unroll
        for (int r = 0; r < 4; r++)
          pw[(rt * 16 + quad * 4 + r) * 40 + nt * 16 + l15] =
              (bf16_t)exp2f(sacc[rt][nt][r] * SC);
    bf16x8 pa0 = *(const bf16x8*)(pw + l15 * 40 + quad * 8);
    bf16x8 pa1 = *(const bf16x8*)(pw + (16 + l15) * 40 + quad * 8);
    lacc[0] = MFMA16(pa0, ones, lacc[0]);
    lacc[1] = MFMA16(pa1, ones, lacc[1]);
    // PV: each V-read feeds 2 MFMA (swizzled chunk read)
    __builtin_amdgcn_s_setprio(1);
#pragma unroll
    for (int ct = 0; ct < 16; ct++) {
      bf16x8 vb = *(const bf16x8*)(vbuf + (ct * 16 + l15) * 32 +
                                   ((quad ^ xrv) << 3));
      oacc[0][ct] = MFMA16(pa0, vb, oacc[0][ct]);
      oacc[1][ct] = MFMA16(pa1, vb, oacc[1][ct]);
    }
    __builtin_amdgcn_s_setprio(0);
    // counted wait: tile t+1 (older 8) resident; tile t+2's 8 stay in flight
    if (t < 70) {
      asm volatile("s_waitcnt vmcnt(8)" ::: "memory");
    } else {
      asm volatile("s_waitcnt vmcnt(0)" ::: "memory");
    }
    __builtin_amdgcn_s_barrier();
    __builtin_amdgcn_sched_barrier(0);
    bc = bc + 1; if (bc >= 3) bc -= 3;
  }

  float inv[2][4];
#pragma unroll
  for (int rt = 0; rt < 2; rt++)
#pragma unroll
    for (int r = 0; r < 4; r++) inv[rt][r] = 1.f / lacc[rt][r];

  // ---- epilogue: y -> A-frags -> W-conv -> wy (d_out scratch) ----
  const bf16_t* Wg = par + P_WW + (size_t)g * CGn * C2n;
  const bf16_t* wbias = par + P_WB + g * CGn;
#pragma unroll
  for (int rt = 0; rt < 2; rt++) {
    bf16x8 yf[8];
#pragma unroll
    for (int kc8 = 0; kc8 < 8; kc8++) {
#pragma unroll
      for (int h = 0; h < 2; h++) {
        int ct = kc8 * 2 + h;
#pragma unroll
        for (int r = 0; r < 4; r++)
          pw[(quad * 4 + r) * 40 + h * 16 + l15] = (bf16_t)(oacc[rt][ct][r] * inv[rt][r]);
      }
      yf[kc8] = *(const bf16x8*)(pw + l15 * 40 + quad * 8);
    }
#pragma unroll
    for (int ot = 0; ot < 8; ot++) {
      f32x4 wyacc = (f32x4){0.f, 0.f, 0.f, 0.f};
#pragma unroll
      for (int ks = 0; ks < 8; ks++) {
        bf16x8 wv = *(const bf16x8*)(Wg + (size_t)(ot * 16 + l15) * C2n + ks * 32 + quad * 8);
        wyacc = MFMA16(yf[ks], wv, wyacc);
      }
      int o = ot * 16 + l15;
      float bv = (float)wbias[o];
#pragma unroll
      for (int r = 0; r < 4; r++)
        wyOut[((size_t)b * Nn + mw0 + rt * 16 + quad * 4 + r) * 512 + g * 128 + o] =
            (bf16_t)(wyacc[r] + bv);
    }
  }
}

// ---------- wy BN stats: vectorized bf16x8 reads + LDS f32 reduce ----------
__global__ __launch_bounds__(256) void k_wy_stats(const bf16_t* __restrict__ wyBF,
                                                  double* __restrict__ stats) {
  __shared__ float sred[1024];
  int b = blockIdx.y, m0 = blockIdx.x * 64, tid = threadIdx.x;
  for (int i = tid; i < 1024; i += 256) sred[i] = 0.f;
  __syncthreads();
  int ch8 = (tid & 63) * 8, r0 = tid >> 6;
  float s[8], q[8];
#pragma unroll
  for (int j = 0; j < 8; j++) { s[j] = 0.f; q[j] = 0.f; }
  for (int k = 0; k < 16; k++) {
    int row = k * 4 + r0;
    bf16x8 v = *(const bf16x8*)(wyBF + ((size_t)b * Nn + m0 + row) * 512 + ch8);
#pragma unroll
    for (int j = 0; j < 8; j++) {
      float f = (float)v[j];
      s[j] += f;
      q[j] += f * f;
    }
  }
#pragma unroll
  for (int j = 0; j < 8; j++) {
    atomicAdd(&sred[ch8 + j], s[j]);
    atomicAdd(&sred[512 + ch8 + j], q[j]);
  }
  __syncthreads();
  for (int i = tid; i < 1024; i += 256) atomicAdd(&stats[i], (double)sred[i]);
}

// ---------- BN scale/shift ----------
__global__ void k_bn_st(const double* __restrict__ stats, const bf16_t* __restrict__ gamma,
                        const bf16_t* __restrict__ beta, float* __restrict__ sArr,
                        float* __restrict__ tArr, double inv_count) {
  int ch = threadIdx.x;  // 512
  double mean = stats[ch] * inv_count;
  double var = stats[512 + ch] * inv_count - mean * mean;
  double s = (double)(float)gamma[ch] / sqrt(var + (double)EPS);
  sArr[ch] = (float)s;
  tArr[ch] = (float)((double)(float)beta[ch] - mean * s);
}

// ---------- fold wy-BN into bottleneck weights ----------
__global__ __launch_bounds__(256) void k_fold(
    const bf16_t* __restrict__ par, const float* __restrict__ sW,
    const float* __restrict__ tW, bf16_t* __restrict__ bcwF, float* __restrict__ biasF) {
  int oo = blockIdx.x;
  int tid = threadIdx.x;
  const bf16_t* row = par + P_BCW + (size_t)oo * 1024;
  bf16_t* orow = bcwF + (size_t)oo * 1024;
  float part = 0.f;
  for (int c = tid; c < 512; c += 256) orow[c] = row[c];
  for (int c = 512 + tid; c < 1024; c += 256) {
    float wv = (float)row[c];
    orow[c] = (bf16_t)(wv * sW[c - 512]);
    part += wv * tW[c - 512];
  }
  __shared__ float red[256];
  red[tid] = part;
  __syncthreads();
  for (int s = 128; s > 0; s >>= 1) {
    if (tid < s) red[tid] += red[tid + s];
    __syncthreads();
  }
  if (tid == 0) biasF[oo] = (float)par[P_BCB + oo] + red[0];
}

// ---------- final GEMM (single pass): stats + unnormalized f32 out ----------
// X-tile staged through LDS (bf16x8); wy B-frags direct-global (R1 structure).
__global__ __launch_bounds__(256) void k_final(
    const bf16_t* __restrict__ xbfT, const bf16_t* __restrict__ wyBF,
    const bf16_t* __restrict__ bcwF, const float* __restrict__ biasF,
    double* __restrict__ stats, float* __restrict__ un) {
  __shared__ alignas(16) bf16_t xsT[64][40];
  int b = blockIdx.z;
  int tid = threadIdx.x, w = tid >> 6, lane = tid & 63;
  int l15 = lane & 15, quad = lane >> 4;
  int oo0 = blockIdx.y * 64 + w * 16;
  int n0 = blockIdx.x * 64;
  int srow = tid >> 2, sch = (tid & 3) * 8;
  const bf16_t* xsrc = xbfT + ((size_t)b * Nn + n0 + srow) * Cn + sch;

  f32x4 acc[4];
#pragma unroll
  for (int j = 0; j < 4; j++) acc[j] = (f32x4){0.f, 0.f, 0.f, 0.f};

  for (int kk = 0; kk < 16; kk++) {
    int c0 = kk * 32;
    __syncthreads();
    *(bf16x8*)(&xsT[srow][sch]) = *(const bf16x8*)(xsrc + c0);
    __syncthreads();
    bf16x8 a = *(const bf16x8*)(bcwF + (size_t)(oo0 + l15) * 1024 + c0 + quad * 8);
#pragma unroll
    for (int j = 0; j < 4; j++) {
      bf16x8 bx = *(const bf16x8*)(&xsT[j * 16 + l15][quad * 8]);
      acc[j] = MFMA16(a, bx, acc[j]);
    }
  }
  for (int kk = 0; kk < 16; kk++) {
    int c0 = kk * 32 + quad * 8;
    bf16x8 a = *(const bf16x8*)(bcwF + (size_t)(oo0 + l15) * 1024 + 512 + c0);
#pragma unroll
    for (int j = 0; j < 4; j++) {
      bf16x8 bw = *(const bf16x8*)(wyBF + ((size_t)b * Nn + n0 + j * 16 + l15) * 512 + c0);
      acc[j] = MFMA16(a, bw, acc[j]);
    }
  }

#pragma unroll
  for (int r = 0; r < 4; r++) {
    int row = oo0 + quad * 4 + r;
    float bv = biasF[row];
    float s = 0.f, q = 0.f;
#pragma unroll
    for (int j = 0; j < 4; j++) {
      float v = acc[j][r] + bv;
      un[((size_t)b * 512 + row) * Nn + n0 + j * 16 + l15] = v;
      s += v;
      q += v * v;
    }
    s += __shfl_xor(s, 1); q += __shfl_xor(q, 1);
    s += __shfl_xor(s, 2); q += __shfl_xor(q, 2);
    s += __shfl_xor(s, 4); q += __shfl_xor(q, 4);
    s += __shfl_xor(s, 8); q += __shfl_xor(q, 8);
    if (l15 == 0) {
      atomicAdd(&stats[row], (double)s);
      atomicAdd(&stats[512 + row], (double)q);
    }
  }
}

// ---------- elementwise normalize: out = un*s[ch] + t[ch] ----------
__global__ __launch_bounds__(256) void k_norm(const float4* __restrict__ un,
                                              const float* __restrict__ sO,
                                              const float* __restrict__ tO,
                                              float4* __restrict__ out) {
  size_t i = (size_t)blockIdx.x * 256 + threadIdx.x;
  if (i >= (size_t)2359296) return;        // 8*512*2304/4
  size_t r = i / 576;                      // b*512 + ch (576 float4 per row)
  int ch = (int)(r & 511);
  float sc = sO[ch], tc = tO[ch];
  float4 v = un[i];
  float4 o;
  o.x = v.x * sc + tc;
  o.y = v.y * sc + tc;
  o.z = v.z * sc + tc;
  o.w = v.w * sc + tc;
  out[i] = o;
}

extern "C" void kernel_launch(void* const* d_in, const int* in_sizes, int n_in,
                              void* d_out, int out_size, void* d_ws, size_t ws_size,
                              hipStream_t stream) {
  const float* feats = (const float*)d_in[0];

  char* ws = (char*)d_ws;
  bf16_t* WPAR = (bf16_t*)(ws + OFF_WPAR);
  float* biasF = (float*)(ws + OFF_BIASF);
  float* sW = (float*)(ws + OFF_SW);
  float* tW = (float*)(ws + OFF_TW2);
  float* sO = (float*)(ws + OFF_SO);
  float* tO = (float*)(ws + OFF_TO);
  double* statsWy = (double*)(ws + OFF_STATW);
  double* statsO = (double*)(ws + OFF_STATO);
  bf16_t* arena = (bf16_t*)(ws + OFF_ARENA);
  bf16_t* bcwF = (bf16_t*)(ws + OVL_BCWF);     // post-attn overlay
  float* unScr = (float*)(ws + OVL_UN);        // post-attn overlay (unnormalized out)
  bf16_t* wyScr = (bf16_t*)d_out;              // d_out lower half: wy scratch
  bf16_t* xbfT = (bf16_t*)((char*)d_out + OFF_XBFT_IN_OUT);  // d_out upper half

  static const unsigned par_off[14] = {
      (unsigned)P_TW, (unsigned)P_TB, (unsigned)P_PW, (unsigned)P_PB,
      (unsigned)P_GW, (unsigned)P_GB, (unsigned)P_WW, (unsigned)P_WB,
      (unsigned)P_WG, (unsigned)P_WBE, (unsigned)P_BCW, (unsigned)P_BCB,
      (unsigned)P_BCG, (unsigned)P_BCBE};
  WArgs wa;
  for (int i = 0; i < 14; i++) {
    wa.src[i] = (const float*)d_in[i + 1];
    wa.n[i] = (unsigned)in_sizes[i + 1];
    wa.off[i] = par_off[i];
  }

  hipMemsetAsync(ws + OFF_STATW, 0, 16384, stream);  // statsWy + statsO

  k_wconv<<<dim3(256, 14), 256, 0, stream>>>(wa, WPAR);
  k_xpose<<<dim3(36, 8, 8), 256, 0, stream>>>(feats, xbfT);
  k_projKV<<<dim3(36, 4, 64), 256, 0, stream>>>(xbfT, WPAR, arena);
  k_attn_wy<<<dim3(18, 32), 256, 0, stream>>>(feats, arena, WPAR, wyScr);
  k_wy_stats<<<dim3(36, 8), 256, 0, stream>>>(wyScr, statsWy);
  k_bn_st<<<1, 512, 0, stream>>>(statsWy, WPAR + P_WG, WPAR + P_WBE, sW, tW, 1.0 / 18432.0);
  k_fold<<<512, 256, 0, stream>>>(WPAR, sW, tW, bcwF, biasF);
  k_final<<<dim3(36, 8, 8), 256, 0, stream>>>(xbfT, wyScr, bcwF, biasF, statsO, unScr);
  k_bn_st<<<1, 512, 0, stream>>>(statsO, WPAR + P_BCG, WPAR + P_BCBE, sO, tO, 1.0 / 18432.0);
  k_norm<<<9216, 256, 0, stream>>>((const float4*)unScr, sO, tO, (float4*)d_out);
}

// Round 10
// 760.812 us; speedup vs baseline: 1.3200x; 1.2370x over previous
//
#include <hip/hip_runtime.h>
#include <hip/hip_bf16.h>

#define EPS 1e-5f
#define Bn 8
#define Cn 512
#define Nn 2304
#define C1n 256
#define C2n 256
#define CGn 128

typedef __bf16 bf16_t;
typedef __bf16 bf16x8 __attribute__((ext_vector_type(8)));
typedef float f32x4 __attribute__((ext_vector_type(4)));

#define MFMA16(a, b, c) __builtin_amdgcn_mfma_f32_16x16x32_bf16(a, b, c, 0, 0, 0)

// async global->LDS DMA, 16B per lane. LDS dest is wave-uniform base + lane*16.
__device__ __forceinline__ void gload16(const bf16_t* g, const bf16_t* l) {
  __builtin_amdgcn_global_load_lds(
      (const __attribute__((address_space(1))) void*)g,
      (__attribute__((address_space(3))) void*)l, 16, 0, 0);
}

// ---------- WPAR element offsets (bf16 weight arena) ----------
static constexpr size_t P_TW = 0;            // (4,256,512)
static constexpr size_t P_TB = 524288;
static constexpr size_t P_PW = 525312;
static constexpr size_t P_PB = 1049600;
static constexpr size_t P_GW = 1050624;
static constexpr size_t P_GB = 1574912;
static constexpr size_t P_WW = 1575936;      // (4,128,256)
static constexpr size_t P_WB = 1707008;
static constexpr size_t P_WG = 1707520;
static constexpr size_t P_WBE = 1708032;
static constexpr size_t P_BCW = 1708544;     // (512,1024)
static constexpr size_t P_BCB = 2232832;
static constexpr size_t P_BCG = 2233344;
static constexpr size_t P_BCBE = 2233856;

// ---------- workspace layout (bytes); end = 79,992,832 (proven safe) ----------
static constexpr size_t OFF_WPAR  = 0;          // 4,468,736
static constexpr size_t OFF_BIASF = 4468736;
static constexpr size_t OFF_SW    = 4470784;
static constexpr size_t OFF_TW2   = 4472832;
static constexpr size_t OFF_SO    = 4474880;
static constexpr size_t OFF_TO    = 4476928;
static constexpr size_t OFF_STATW = 4478976;    // f64[1024]
static constexpr size_t OFF_STATO = 4487168;    // f64[1024]
static constexpr size_t OFF_ARENA = 4495360;    // 32 slots x (K+V) = 75,497,472
static constexpr size_t QS  = 589824;           // elems: 2304*256
static constexpr size_t SL2 = 2 * QS;           // elems per slot (K,V)
// post-attn overlays inside the dead arena:
static constexpr size_t OVL_BCWF = OFF_ARENA;             // 1,048,576
static constexpr size_t OVL_UN   = OFF_ARENA + 2097152;   // 37,748,736 (unnormalized f32 out)
// d_out partitioning during the run:
//   [0, 18874368)        : wy scratch (bf16), written by attn, read by stats/final
//   [18874368, 37748736) : xbfT (bf16 [B][N][C]), written by k_xpose, read by
//                          projKV / k_final; clobbered only by k_norm at the end
static constexpr size_t OFF_XBFT_IN_OUT = 18874368;

// ---------- K0: convert 14 f32 weight inputs -> bf16 WPAR ----------
struct WArgs {
  const float* src[14];
  unsigned n[14];
  unsigned off[14];
};

__global__ __launch_bounds__(256) void k_wconv(WArgs a, bf16_t* __restrict__ par) {
  int which = blockIdx.y;
  const float* s = a.src[which];
  unsigned n = a.n[which];
  bf16_t* dst = par + a.off[which];
  size_t stride = (size_t)gridDim.x * blockDim.x;
  for (size_t i = (size_t)blockIdx.x * blockDim.x + threadIdx.x; i < n; i += stride)
    dst[i] = (bf16_t)s[i];
}

// ---------- K0b: feats (B,C,N) f32 -> xbfT (B,N,C) bf16 via LDS tile transpose ----------
__global__ __launch_bounds__(256) void k_xpose(const float* __restrict__ feats,
                                               bf16_t* __restrict__ xbfT) {
  __shared__ bf16_t tile[64][72];
  int b = blockIdx.z, c0 = blockIdx.y * 64, n0 = blockIdx.x * 64;
  int tid = threadIdx.x;
  int cl = tid >> 4, nl4 = (tid & 15) * 4;
#pragma unroll
  for (int e = 0; e < 4; e++) {
    int c = e * 16 + cl;
    float4 v = *(const float4*)(feats + ((size_t)b * Cn + c0 + c) * Nn + n0 + nl4);
    tile[nl4 + 0][c] = (bf16_t)v.x;
    tile[nl4 + 1][c] = (bf16_t)v.y;
    tile[nl4 + 2][c] = (bf16_t)v.z;
    tile[nl4 + 3][c] = (bf16_t)v.w;
  }
  __syncthreads();
  int r = tid >> 2, ch = tid & 3;
#pragma unroll
  for (int e = 0; e < 2; e++) {
    int cc = (ch + e * 4) * 8;  // 0..63
    bf16x8 v = *(const bf16x8*)(&tile[r][cc]);
    *(bf16x8*)(xbfT + ((size_t)b * Nn + n0 + r) * Cn + c0 + cc) = v;
  }
}

// ---------- K1 v2: projections as 128x128-tile single-barrier GEMM ----------
// grid (18, 2, 64): x = 128-row n-block, y = 128-col (p=0: c1 half; p=1: c2 half),
// z = slot*2+p. X-tile [128][40] padded LDS, reg-staged double buffer, 1 barrier
// per 32-K step (write target disjoint from read target). Weights direct (L2).
// 4 waves: wh=w>>1 row-half, wl=w&1 col-half; acc[4][4] per wave (64x64).
__global__ __launch_bounds__(256) void k_projKV(
    const bf16_t* __restrict__ xbfT, const bf16_t* __restrict__ par,
    bf16_t* __restrict__ arena) {
  __shared__ alignas(16) bf16_t xsT[2][5120];  // [128][40] x2
  int z = blockIdx.z, s = z >> 1, p = z & 1;
  int g = s >> 3, b = s & 7;
  int tid = threadIdx.x, w = tid >> 6, lane = tid & 63;
  int l15 = lane & 15, quad = lane >> 4;
  int wh = w >> 1, wl = w & 1;
  int n0 = blockIdx.x * 128;   // staged X rows (n for p=1, m for p=0)
  int y0 = blockIdx.y * 128;   // output col/row half base

  // staging: thread covers row tid>>1, 32B (two bf16x8) at col (tid&1)*16
  int srow = tid >> 1, sc0 = (tid & 1) * 16;
  const bf16_t* xrow = xbfT + ((size_t)b * Nn + n0 + srow) * Cn + sc0;
  bf16_t* st0 = &xsT[0][srow * 40 + sc0];
  bf16_t* st1 = &xsT[1][srow * 40 + sc0];

  f32x4 acc[4][4];
#pragma unroll
  for (int i = 0; i < 4; i++)
#pragma unroll
    for (int j = 0; j < 4; j++) acc[i][j] = (f32x4){0.f, 0.f, 0.f, 0.f};

  const bf16_t* W = par + (p == 0 ? P_PW : P_GW) + (size_t)g * 256 * Cn;

  // prologue: stage kk=0 into buf 0
  {
    bf16x8 r0 = *(const bf16x8*)(xrow);
    bf16x8 r1 = *(const bf16x8*)(xrow + 8);
    *(bf16x8*)(st0) = r0;
    *(bf16x8*)(st1 - (st1 - st0)) = r0;  // no-op guard (kept simple below)
    *(bf16x8*)(st0 + 8) = r1;
  }
  __syncthreads();

  int cur = 0;
  for (int kk = 0; kk < 16; kk++) {
    bf16x8 nx0, nx1;
    if (kk < 15) {
      nx0 = *(const bf16x8*)(xrow + (kk + 1) * 32);
      nx1 = *(const bf16x8*)(xrow + (kk + 1) * 32 + 8);
    }
    int c0 = kk * 32 + quad * 8;
    // W frags: rows y0 + wl*64 (p=0 cols) or y0 + wh*64 (p=1 rows)
    int wbase = y0 + (p == 0 ? wl : wh) * 64;
    bf16x8 wf[4];
#pragma unroll
    for (int j = 0; j < 4; j++)
      wf[j] = *(const bf16x8*)(W + (size_t)(wbase + j * 16 + l15) * Cn + c0);
    // X frags: rows wh*64 (p=0) or wl*64 (p=1)
    int xbase = (p == 0 ? wh : wl) * 64;
    const bf16_t* xb = &xsT[cur][0];
#pragma unroll
    for (int i = 0; i < 4; i++) {
      bf16x8 xf = *(const bf16x8*)(xb + (xbase + i * 16 + l15) * 40 + quad * 8);
      if (p == 0) {
#pragma unroll
        for (int j = 0; j < 4; j++) acc[i][j] = MFMA16(xf, wf[j], acc[i][j]);
      } else {
#pragma unroll
        for (int j = 0; j < 4; j++) acc[j][i] = MFMA16(wf[j], xf, acc[j][i]);
      }
    }
    if (kk < 15) {
      bf16_t* st = (cur == 0) ? st1 : st0;
      *(bf16x8*)(st) = nx0;
      *(bf16x8*)(st + 8) = nx1;
    }
    __syncthreads();
    cur ^= 1;
  }

  if (p == 0) {
    // out[n][c1], chunk-swizzled K layout. acc[i][j]: rows n, cols c1.
    const bf16_t* bias = par + P_PB + g * C1n;
    bf16_t* out = arena + (size_t)s * SL2;
#pragma unroll
    for (int j = 0; j < 4; j++) {
      int col = y0 + wl * 64 + j * 16 + l15;
      int chk = col >> 3, ci = col & 7;
      float bv = (float)bias[col];
#pragma unroll
      for (int i = 0; i < 4; i++)
#pragma unroll
        for (int r = 0; r < 4; r++) {
          int row = n0 + wh * 64 + i * 16 + quad * 4 + r;
          out[(size_t)row * C1n + ((chk ^ (row & 7)) << 3) + ci] =
              (bf16_t)(acc[i][j][r] + bv);
        }
    }
  } else {
    // out[c2][n]. acc[j][i]: D rows = W rows (c2) indexed j, cols = n indexed i.
    const bf16_t* bias = par + P_GB + g * C2n;
    bf16_t* out = arena + (size_t)s * SL2 + QS;
#pragma unroll
    for (int j = 0; j < 4; j++)
#pragma unroll
      for (int r = 0; r < 4; r++) {
        int row = y0 + wh * 64 + j * 16 + quad * 4 + r;
        float bv = (float)bias[row];
#pragma unroll
        for (int i = 0; i < 4; i++)
          out[(size_t)row * Nn + n0 + wl * 64 + i * 16 + l15] =
              (bf16_t)(acc[j][i][r] + bv);
      }
  }
}

// ---------- K2: attention — R6 structure verbatim (best measured: 435 us) ----------
// 4 waves x 32 rows, gload_lds double buffer, 1 syncthreads/iter, K+V chunk swizzles.
// LDS: K0|K1 [32x256]x2, V0|V1 [256x32]x2, pw 4x32x40 = 75,776 B.
__global__ __launch_bounds__(256, 2) void k_attn_wy(
    const float* __restrict__ feats, const bf16_t* __restrict__ arena,
    const bf16_t* __restrict__ par, bf16_t* __restrict__ wyOut) {
  __shared__ alignas(16) bf16_t sh[32768 + 5120];

  int mblk = blockIdx.x, gb = blockIdx.y;
  int g = gb >> 3, b = gb & 7;
  const bf16_t* Kp = arena + (size_t)gb * SL2;
  const bf16_t* Vp = Kp + QS;

  int tid = threadIdx.x, w = tid >> 6, lane = tid & 63;
  int l15 = lane & 15, quad = lane >> 4;
  int m0 = mblk * 128;
  int mw0 = m0 + w * 32;
  int w64 = w << 6;
  bf16_t* pw = sh + 32768 + w * 1280;  // per-wave 32x40

  // ---- phase Q: qf[rt*8+kc8] = Q A-frags for this wave's 32 rows ----
  bf16x8 qf[16];
  {
    bf16_t* xs = sh + 24576 + w * 1280;  // per-wave 32x40 scratch (V1 region)
    const bf16_t* Wt = par + P_TW + (size_t)g * C1n * Cn;
    const bf16_t* tb = par + P_TB + g * C1n;
    f32x4 qacc[2][16];
#pragma unroll
    for (int rt = 0; rt < 2; rt++)
#pragma unroll
      for (int ot = 0; ot < 16; ot++) qacc[rt][ot] = (f32x4){0.f, 0.f, 0.f, 0.f};

    for (int kc = 0; kc < 16; kc++) {
#pragma unroll
      for (int ps = 0; ps < 4; ps++) {
        int idx = ps * 64 + lane;
        int cc = idx >> 3;
        int nn = (idx & 7) * 4;
        const float4 v =
            *(const float4*)(feats + ((size_t)b * Cn + kc * 32 + cc) * Nn + mw0 + nn);
        xs[(nn + 0) * 40 + cc] = (bf16_t)v.x;
        xs[(nn + 1) * 40 + cc] = (bf16_t)v.y;
        xs[(nn + 2) * 40 + cc] = (bf16_t)v.z;
        xs[(nn + 3) * 40 + cc] = (bf16_t)v.w;
      }
#pragma unroll
      for (int rt = 0; rt < 2; rt++) {
        bf16x8 a = *(const bf16x8*)(xs + (rt * 16 + l15) * 40 + quad * 8);
#pragma unroll
        for (int ot = 0; ot < 16; ot++) {
          bf16x8 bw = *(const bf16x8*)(Wt + (size_t)(ot * 16 + l15) * Cn + kc * 32 + quad * 8);
          qacc[rt][ot] = MFMA16(a, bw, qacc[rt][ot]);
        }
      }
    }
#pragma unroll
    for (int rt = 0; rt < 2; rt++)
#pragma unroll
      for (int kc8 = 0; kc8 < 8; kc8++) {
#pragma unroll
        for (int h = 0; h < 2; h++) {
          int ot = kc8 * 2 + h;
          float bv = (float)tb[ot * 16 + l15];
#pragma unroll
          for (int r = 0; r < 4; r++)
            pw[(quad * 4 + r) * 40 + h * 16 + l15] = (bf16_t)(qacc[rt][ot][r] + bv);
        }
        qf[rt * 8 + kc8] = *(const bf16x8*)(pw + l15 * 40 + quad * 8);
      }
  }

  f32x4 oacc[2][16];
#pragma unroll
  for (int rt = 0; rt < 2; rt++)
#pragma unroll
    for (int ct = 0; ct < 16; ct++) oacc[rt][ct] = (f32x4){0.f, 0.f, 0.f, 0.f};
  f32x4 lacc[2];
  lacc[0] = (f32x4){0.f, 0.f, 0.f, 0.f};
  lacc[1] = (f32x4){0.f, 0.f, 0.f, 0.f};

  bf16x8 ones;
#pragma unroll
  for (int i = 0; i < 8; i++) ones[i] = (bf16_t)1.0f;
  const float SC = 0.0625f * 1.44269504088896f;

#pragma unroll
  for (int e = 0; e < 4; e++) {
    int cid = e * 256 + tid;
    gload16(Kp + (size_t)(cid >> 5) * C1n + ((cid & 31) << 3),
            sh + ((e << 8) + w64) * 8);
    gload16(Vp + (size_t)(cid >> 2) * Nn + ((((cid & 3) ^ ((cid >> 3) & 3))) << 3),
            sh + 16384 + ((e << 8) + w64) * 8);
  }
  __syncthreads();

  int cur = 0;
  int xrk = l15 & 7;
  int xrv = (l15 >> 1) & 3;
  for (int t = 0; t < 72; t++) {
    if (t < 71) {
      int nn0 = (t + 1) * 32;
      bf16_t* kd = sh + (cur ^ 1) * 8192;
      bf16_t* vd = sh + 16384 + (cur ^ 1) * 8192;
#pragma unroll
      for (int e = 0; e < 4; e++) {
        int cid = e * 256 + tid;
        gload16(Kp + (size_t)(nn0 + (cid >> 5)) * C1n + ((cid & 31) << 3),
                kd + ((e << 8) + w64) * 8);
        gload16(Vp + (size_t)(cid >> 2) * Nn + nn0 + ((((cid & 3) ^ ((cid >> 3) & 3))) << 3),
                vd + ((e << 8) + w64) * 8);
      }
    }
    const bf16_t* kbuf = sh + cur * 8192;
    const bf16_t* vbuf = sh + 16384 + cur * 8192;

    f32x4 sacc[2][2];
#pragma unroll
    for (int rt = 0; rt < 2; rt++)
#pragma unroll
      for (int nt = 0; nt < 2; nt++) sacc[rt][nt] = (f32x4){0.f, 0.f, 0.f, 0.f};
    __builtin_amdgcn_s_setprio(1);
#pragma unroll
    for (int ks = 0; ks < 8; ks++) {
#pragma unroll
      for (int nt = 0; nt < 2; nt++) {
        bf16x8 kb = *(const bf16x8*)(kbuf + (nt * 16 + l15) * 256 +
                                     (((ks * 4 + quad) ^ xrk) << 3));
        sacc[0][nt] = MFMA16(qf[ks], kb, sacc[0][nt]);
        sacc[1][nt] = MFMA16(qf[8 + ks], kb, sacc[1][nt]);
      }
    }
    __builtin_amdgcn_s_setprio(0);
#pragma unroll
    for (int rt = 0; rt < 2; rt++)
#pragma unroll
      for (int nt = 0; nt < 2; nt++)
#pragma unroll
        for (int r = 0; r < 4; r++)
          pw[(rt * 16 + quad * 4 + r) * 40 + nt * 16 + l15] =
              (bf16_t)exp2f(sacc[rt][nt][r] * SC);
    bf16x8 pa0 = *(const bf16x8*)(pw + l15 * 40 + quad * 8);
    bf16x8 pa1 = *(const bf16x8*)(pw + (16 + l15) * 40 + quad * 8);
    lacc[0] = MFMA16(pa0, ones, lacc[0]);
    lacc[1] = MFMA16(pa1, ones, lacc[1]);
    __builtin_amdgcn_s_setprio(1);
#pragma unroll
    for (int ct = 0; ct < 16; ct++) {
      bf16x8 vb = *(const bf16x8*)(vbuf + (ct * 16 + l15) * 32 +
                                   ((quad ^ xrv) << 3));
      oacc[0][ct] = MFMA16(pa0, vb, oacc[0][ct]);
      oacc[1][ct] = MFMA16(pa1, vb, oacc[1][ct]);
    }
    __builtin_amdgcn_s_setprio(0);
    __syncthreads();
    cur ^= 1;
  }

  float inv[2][4];
#pragma unroll
  for (int rt = 0; rt < 2; rt++)
#pragma unroll
    for (int r = 0; r < 4; r++) inv[rt][r] = 1.f / lacc[rt][r];

  const bf16_t* Wg = par + P_WW + (size_t)g * CGn * C2n;
  const bf16_t* wbias = par + P_WB + g * CGn;
#pragma unroll
  for (int rt = 0; rt < 2; rt++) {
    bf16x8 yf[8];
#pragma unroll
    for (int kc8 = 0; kc8 < 8; kc8++) {
#pragma unroll
      for (int h = 0; h < 2; h++) {
        int ct = kc8 * 2 + h;
#pragma unroll
        for (int r = 0; r < 4; r++)
          pw[(quad * 4 + r) * 40 + h * 16 + l15] = (bf16_t)(oacc[rt][ct][r] * inv[rt][r]);
      }
      yf[kc8] = *(const bf16x8*)(pw + l15 * 40 + quad * 8);
    }
#pragma unroll
    for (int ot = 0; ot < 8; ot++) {
      f32x4 wyacc = (f32x4){0.f, 0.f, 0.f, 0.f};
#pragma unroll
      for (int ks = 0; ks < 8; ks++) {
        bf16x8 wv = *(const bf16x8*)(Wg + (size_t)(ot * 16 + l15) * C2n + ks * 32 + quad * 8);
        wyacc = MFMA16(yf[ks], wv, wyacc);
      }
      int o = ot * 16 + l15;
      float bv = (float)wbias[o];
#pragma unroll
      for (int r = 0; r < 4; r++)
        wyOut[((size_t)b * Nn + mw0 + rt * 16 + quad * 4 + r) * 512 + g * 128 + o] =
            (bf16_t)(wyacc[r] + bv);
    }
  }
}

// ---------- wy BN stats: vectorized bf16x8 reads + LDS f32 reduce ----------
__global__ __launch_bounds__(256) void k_wy_stats(const bf16_t* __restrict__ wyBF,
                                                  double* __restrict__ stats) {
  __shared__ float sred[1024];
  int b = blockIdx.y, m0 = blockIdx.x * 64, tid = threadIdx.x;
  for (int i = tid; i < 1024; i += 256) sred[i] = 0.f;
  __syncthreads();
  int ch8 = (tid & 63) * 8, r0 = tid >> 6;
  float s[8], q[8];
#pragma unroll
  for (int j = 0; j < 8; j++) { s[j] = 0.f; q[j] = 0.f; }
  for (int k = 0; k < 16; k++) {
    int row = k * 4 + r0;
    bf16x8 v = *(const bf16x8*)(wyBF + ((size_t)b * Nn + m0 + row) * 512 + ch8);
#pragma unroll
    for (int j = 0; j < 8; j++) {
      float f = (float)v[j];
      s[j] += f;
      q[j] += f * f;
    }
  }
#pragma unroll
  for (int j = 0; j < 8; j++) {
    atomicAdd(&sred[ch8 + j], s[j]);
    atomicAdd(&sred[512 + ch8 + j], q[j]);
  }
  __syncthreads();
  for (int i = tid; i < 1024; i += 256) atomicAdd(&stats[i], (double)sred[i]);
}

// ---------- BN scale/shift ----------
__global__ void k_bn_st(const double* __restrict__ stats, const bf16_t* __restrict__ gamma,
                        const bf16_t* __restrict__ beta, float* __restrict__ sArr,
                        float* __restrict__ tArr, double inv_count) {
  int ch = threadIdx.x;  // 512
  double mean = stats[ch] * inv_count;
  double var = stats[512 + ch] * inv_count - mean * mean;
  double s = (double)(float)gamma[ch] / sqrt(var + (double)EPS);
  sArr[ch] = (float)s;
  tArr[ch] = (float)((double)(float)beta[ch] - mean * s);
}

// ---------- fold wy-BN into bottleneck weights ----------
__global__ __launch_bounds__(256) void k_fold(
    const bf16_t* __restrict__ par, const float* __restrict__ sW,
    const float* __restrict__ tW, bf16_t* __restrict__ bcwF, float* __restrict__ biasF) {
  int oo = blockIdx.x;
  int tid = threadIdx.x;
  const bf16_t* row = par + P_BCW + (size_t)oo * 1024;
  bf16_t* orow = bcwF + (size_t)oo * 1024;
  float part = 0.f;
  for (int c = tid; c < 512; c += 256) orow[c] = row[c];
  for (int c = 512 + tid; c < 1024; c += 256) {
    float wv = (float)row[c];
    orow[c] = (bf16_t)(wv * sW[c - 512]);
    part += wv * tW[c - 512];
  }
  __shared__ float red[256];
  red[tid] = part;
  __syncthreads();
  for (int s = 128; s > 0; s >>= 1) {
    if (tid < s) red[tid] += red[tid + s];
    __syncthreads();
  }
  if (tid == 0) biasF[oo] = (float)par[P_BCB + oo] + red[0];
}

// ---------- K final v2: 128x128-tile single-barrier GEMM, stats + un out ----------
// grid (18, 4, 8): x = 128-n block, y = 128-oo block, z = b. 32 K-steps:
// 0..15 B-rows from xbfT (K=512), 16..31 from wy (K=512). A = bcwF direct (L2).
__global__ __launch_bounds__(256) void k_final(
    const bf16_t* __restrict__ xbfT, const bf16_t* __restrict__ wyBF,
    const bf16_t* __restrict__ bcwF, const float* __restrict__ biasF,
    double* __restrict__ stats, float* __restrict__ un) {
  __shared__ alignas(16) bf16_t xsT[2][5120];  // [128][40] x2
  int b = blockIdx.z;
  int tid = threadIdx.x, w = tid >> 6, lane = tid & 63;
  int l15 = lane & 15, quad = lane >> 4;
  int wh = w >> 1, wl = w & 1;
  int n0 = blockIdx.x * 128;
  int oo0 = blockIdx.y * 128;

  int srow = tid >> 1, sc0 = (tid & 1) * 16;
  const bf16_t* xrow = xbfT + ((size_t)b * Nn + n0 + srow) * Cn + sc0;
  const bf16_t* wrow = wyBF + ((size_t)b * Nn + n0 + srow) * 512 + sc0;
  bf16_t* stA = &xsT[0][srow * 40 + sc0];
  bf16_t* stB = &xsT[1][srow * 40 + sc0];

  f32x4 acc[4][4];  // [i: oo frag][j: n frag]
#pragma unroll
  for (int i = 0; i < 4; i++)
#pragma unroll
    for (int j = 0; j < 4; j++) acc[i][j] = (f32x4){0.f, 0.f, 0.f, 0.f};

  // prologue: stage kk=0 (xbfT)
  {
    bf16x8 r0 = *(const bf16x8*)(xrow);
    bf16x8 r1 = *(const bf16x8*)(xrow + 8);
    *(bf16x8*)(stA) = r0;
    *(bf16x8*)(stA + 8) = r1;
  }
  __syncthreads();

  int cur = 0;
  for (int kk = 0; kk < 32; kk++) {
    bf16x8 nx0, nx1;
    if (kk < 31) {
      const bf16_t* src = (kk + 1 < 16) ? (xrow + (kk + 1) * 32)
                                        : (wrow + (kk + 1 - 16) * 32);
      nx0 = *(const bf16x8*)(src);
      nx1 = *(const bf16x8*)(src + 8);
    }
    int c0 = (kk < 16 ? kk * 32 : 512 + (kk - 16) * 32) + quad * 8;
    bf16x8 af[4];
#pragma unroll
    for (int i = 0; i < 4; i++)
      af[i] = *(const bf16x8*)(bcwF + (size_t)(oo0 + wh * 64 + i * 16 + l15) * 1024 + c0);
    const bf16_t* xb = &xsT[cur][0];
#pragma unroll
    for (int j = 0; j < 4; j++) {
      bf16x8 bf = *(const bf16x8*)(xb + (wl * 64 + j * 16 + l15) * 40 + quad * 8);
#pragma unroll
      for (int i = 0; i < 4; i++) acc[i][j] = MFMA16(af[i], bf, acc[i][j]);
    }
    if (kk < 31) {
      bf16_t* st = (cur == 0) ? stB : stA;
      *(bf16x8*)(st) = nx0;
      *(bf16x8*)(st + 8) = nx1;
    }
    __syncthreads();
    cur ^= 1;
  }

#pragma unroll
  for (int i = 0; i < 4; i++)
#pragma unroll
    for (int r = 0; r < 4; r++) {
      int row = oo0 + wh * 64 + i * 16 + quad * 4 + r;
      float bv = biasF[row];
      float s = 0.f, q = 0.f;
#pragma unroll
      for (int j = 0; j < 4; j++) {
        float v = acc[i][j][r] + bv;
        un[((size_t)b * 512 + row) * Nn + n0 + wl * 64 + j * 16 + l15] = v;
        s += v;
        q += v * v;
      }
      s += __shfl_xor(s, 1); q += __shfl_xor(q, 1);
      s += __shfl_xor(s, 2); q += __shfl_xor(q, 2);
      s += __shfl_xor(s, 4); q += __shfl_xor(q, 4);
      s += __shfl_xor(s, 8); q += __shfl_xor(q, 8);
      if (l15 == 0) {
        atomicAdd(&stats[row], (double)s);
        atomicAdd(&stats[512 + row], (double)q);
      }
    }
}

// ---------- elementwise normalize: out = un*s[ch] + t[ch] ----------
__global__ __launch_bounds__(256) void k_norm(const float4* __restrict__ un,
                                              const float* __restrict__ sO,
                                              const float* __restrict__ tO,
                                              float4* __restrict__ out) {
  size_t i = (size_t)blockIdx.x * 256 + threadIdx.x;
  if (i >= (size_t)2359296) return;        // 8*512*2304/4
  size_t r = i / 576;                      // b*512 + ch (576 float4 per row)
  int ch = (int)(r & 511);
  float sc = sO[ch], tc = tO[ch];
  float4 v = un[i];
  float4 o;
  o.x = v.x * sc + tc;
  o.y = v.y * sc + tc;
  o.z = v.z * sc + tc;
  o.w = v.w * sc + tc;
  out[i] = o;
}

extern "C" void kernel_launch(void* const* d_in, const int* in_sizes, int n_in,
                              void* d_out, int out_size, void* d_ws, size_t ws_size,
                              hipStream_t stream) {
  const float* feats = (const float*)d_in[0];

  char* ws = (char*)d_ws;
  bf16_t* WPAR = (bf16_t*)(ws + OFF_WPAR);
  float* biasF = (float*)(ws + OFF_BIASF);
  float* sW = (float*)(ws + OFF_SW);
  float* tW = (float*)(ws + OFF_TW2);
  float* sO = (float*)(ws + OFF_SO);
  float* tO = (float*)(ws + OFF_TO);
  double* statsWy = (double*)(ws + OFF_STATW);
  double* statsO = (double*)(ws + OFF_STATO);
  bf16_t* arena = (bf16_t*)(ws + OFF_ARENA);
  bf16_t* bcwF = (bf16_t*)(ws + OVL_BCWF);     // post-attn overlay
  float* unScr = (float*)(ws + OVL_UN);        // post-attn overlay (unnormalized out)
  bf16_t* wyScr = (bf16_t*)d_out;              // d_out lower half: wy scratch
  bf16_t* xbfT = (bf16_t*)((char*)d_out + OFF_XBFT_IN_OUT);  // d_out upper half

  static const unsigned par_off[14] = {
      (unsigned)P_TW, (unsigned)P_TB, (unsigned)P_PW, (unsigned)P_PB,
      (unsigned)P_GW, (unsigned)P_GB, (unsigned)P_WW, (unsigned)P_WB,
      (unsigned)P_WG, (unsigned)P_WBE, (unsigned)P_BCW, (unsigned)P_BCB,
      (unsigned)P_BCG, (unsigned)P_BCBE};
  WArgs wa;
  for (int i = 0; i < 14; i++) {
    wa.src[i] = (const float*)d_in[i + 1];
    wa.n[i] = (unsigned)in_sizes[i + 1];
    wa.off[i] = par_off[i];
  }

  hipMemsetAsync(ws + OFF_STATW, 0, 16384, stream);  // statsWy + statsO

  k_wconv<<<dim3(256, 14), 256, 0, stream>>>(wa, WPAR);
  k_xpose<<<dim3(36, 8, 8), 256, 0, stream>>>(feats, xbfT);
  k_projKV<<<dim3(18, 2, 64), 256, 0, stream>>>(xbfT, WPAR, arena);
  k_attn_wy<<<dim3(18, 32), 256, 0, stream>>>(feats, arena, WPAR, wyScr);
  k_wy_stats<<<dim3(36, 8), 256, 0, stream>>>(wyScr, statsWy);
  k_bn_st<<<1, 512, 0, stream>>>(statsWy, WPAR + P_WG, WPAR + P_WBE, sW, tW, 1.0 / 18432.0);
  k_fold<<<512, 256, 0, stream>>>(WPAR, sW, tW, bcwF, biasF);
  k_final<<<dim3(18, 4, 8), 256, 0, stream>>>(xbfT, wyScr, bcwF, biasF, statsO, unScr);
  k_bn_st<<<1, 512, 0, stream>>>(statsO, WPAR + P_BCG, WPAR + P_BCBE, sO, tO, 1.0 / 18432.0);
  k_norm<<<9216, 256, 0, stream>>>((const float4*)unScr, sO, tO, (float4*)d_out);
}